// Round 2
// baseline (429.127 us; speedup 1.0000x reference)
//
#include <hip/hip_runtime.h>

#define N_SAMP 16384
#define D_FEAT 64
#define TILE 128
#define NTILE (N_SAMP / TILE)         // 128
#define TOTAL_BLOCKS (NTILE * NTILE)  // 16384 dispatched (half early-exit)

typedef __attribute__((ext_vector_type(8))) short bf16x8;
typedef __attribute__((ext_vector_type(4))) float f32x4;
typedef __attribute__((ext_vector_type(2))) float f32x2;
typedef __attribute__((ext_vector_type(4))) unsigned short u16x4;

typedef __attribute__((address_space(3))) unsigned lds_u32_t;
typedef const __attribute__((address_space(1))) unsigned glb_u32_t;

// ws scalar block (after xb): [tsum, sa, sxi, sy, cnt(u32), pad...]
struct Accs {
  float tsum, sa, sxi, sy;
  unsigned cnt;
  unsigned pad[3];
};

__device__ __forceinline__ void load16_to_lds(const void* g, void* l) {
  __builtin_amdgcn_global_load_lds((glb_u32_t*)g, (lds_u32_t*)l, 16, 0, 0);
}

__device__ __forceinline__ unsigned short f2bf_rne(float f) {
  union { float f; unsigned u; } v;
  v.f = f;
  unsigned u = v.u;
  return (unsigned short)((u + 0x7FFFu + ((u >> 16) & 1u)) >> 16);
}

// Prepass: xb[i][k] = bf16(y_i * x[i][k]); fused Sa/Sxi/Sy reductions.
__global__ __launch_bounds__(256) void prep_kernel(
    const float* __restrict__ x, const float* __restrict__ y,
    const float* __restrict__ alpha, const float* __restrict__ xi,
    unsigned short* __restrict__ xb, Accs* __restrict__ accs) {
  int t = blockIdx.x * 256 + threadIdx.x;  // 0 .. 262143
  int base = t * 4;
  int row = base >> 6;  // D=64
  float yv = y[row];
  float4 v = *(const float4*)(x + base);
  u16x4 o;
  o.x = f2bf_rne(v.x * yv);
  o.y = f2bf_rne(v.y * yv);
  o.z = f2bf_rne(v.z * yv);
  o.w = f2bf_rne(v.w * yv);
  *(u16x4*)(xb + base) = o;

  // Blocks 0..63 cover t = 0..16383 exactly: reduce relu(alpha), relu(xi), y.
  if (blockIdx.x < (N_SAMP / 256)) {
    float a = fmaxf(alpha[t], 0.0f);
    float xr = fmaxf(xi[t], 0.0f);
    float yy = y[t];
#pragma unroll
    for (int off = 32; off > 0; off >>= 1) {
      a += __shfl_down(a, off, 64);
      xr += __shfl_down(xr, off, 64);
      yy += __shfl_down(yy, off, 64);
    }
    if ((threadIdx.x & 63) == 0) {
      atomicAdd(&accs->sa, a);
      atomicAdd(&accs->sxi, xr);
      atomicAdd(&accs->sy, yy);
    }
  }
}

// Symmetric traversal: block (bx,by) computes Gram tile (I0=by*128, J0=bx*128)
// only for J0 >= I0. Off-diagonal tiles are weighted by (a_i + a_j) since
// tile (J,I) is the transpose. acc init = y_i*y_j*coeff; MFMA adds
// (y_i x_i)·(y_j x_j) => T = y_i y_j (g+coeff); odd deg => T^d = y_i y_j K^d.
__global__ __launch_bounds__(256, 2) void tile_kernel(
    const unsigned short* __restrict__ xb,
    const float* __restrict__ alpha,
    const float* __restrict__ y,
    const int* __restrict__ coeffp,
    const int* __restrict__ degp,
    const float* __restrict__ bp,
    const int* __restrict__ Cp,
    const int* __restrict__ lamp,
    Accs* __restrict__ accs,
    float* __restrict__ out) {
  __shared__ unsigned short smA[128 * 64];
  __shared__ unsigned short smB[128 * 64];
  __shared__ float wred[4];

  const int tid = threadIdx.x;
  const int I0 = blockIdx.y * 128;
  const int J0 = blockIdx.x * 128;
  const bool active = (J0 >= I0);

  float blocksum = 0.0f;

  if (active) {
    const int lane = tid & 63;
    const int wv = tid >> 6;  // wave 0..3
    const int wm = wv >> 1;   // wave row (0..1)
    const int wn = wv & 1;    // wave col (0..1)
    const int lr = lane & 15;
    const int q = lane >> 4;  // quad 0..3
    const bool diag = (J0 == I0);

    // ---- stage A (rows I0..) and B (rows J0..) tiles, XOR-swizzled ----
    const char* xbytes = (const char*)xb;
    char* smAb = (char*)smA;
    char* smBb = (char*)smB;
#pragma unroll
    for (int it = 0; it < 4; ++it) {
      int slotbase = it * 256 + wv * 64;  // wave-uniform
      int S = slotbase + lane;
      int r = S >> 3;
      int c = (S & 7) ^ (r & 7);
      load16_to_lds(xbytes + (((size_t)(I0 + r)) << 7) + (c << 4),
                    smAb + (slotbase << 4));
      load16_to_lds(xbytes + (((size_t)(J0 + r)) << 7) + (c << 4),
                    smBb + (slotbase << 4));
    }

    const float fco = (float)coeffp[0];
    const int deg = degp[0];

    float4 yrow[4];
    float4 arow[4];
    float ycol[4], wcol[4];
#pragma unroll
    for (int mt = 0; mt < 4; ++mt) {
      int i = I0 + wm * 64 + mt * 16 + q * 4;
      yrow[mt] = *(const float4*)(y + i);
      float4 av = *(const float4*)(alpha + i);
      arow[mt].x = fmaxf(av.x, 0.0f);
      arow[mt].y = fmaxf(av.y, 0.0f);
      arow[mt].z = fmaxf(av.z, 0.0f);
      arow[mt].w = fmaxf(av.w, 0.0f);
    }
#pragma unroll
    for (int nt = 0; nt < 4; ++nt) {
      int j = J0 + wn * 64 + nt * 16 + lr;
      ycol[nt] = y[j];
      wcol[nt] = fmaxf(alpha[j], 0.0f);
    }

    // acc[mt][nt] element rg -> C[row = q*4+rg][col = lr] (m89/m91 layout)
    f32x4 acc[4][4];
#pragma unroll
    for (int mt = 0; mt < 4; ++mt) {
      f32x2 yr0 = {yrow[mt].x, yrow[mt].y};
      f32x2 yr1 = {yrow[mt].z, yrow[mt].w};
#pragma unroll
      for (int nt = 0; nt < 4; ++nt) {
        float s = ycol[nt] * fco;
        f32x2 lo = yr0 * s;
        f32x2 hi = yr1 * s;
        acc[mt][nt][0] = lo.x;
        acc[mt][nt][1] = lo.y;
        acc[mt][nt][2] = hi.x;
        acc[mt][nt][3] = hi.y;
      }
    }

    __syncthreads();  // drains global_load_lds (vmcnt)

    // ---- LDS -> frags: A[m=lr][k=q*8+j] ----
    bf16x8 af[4][2], bfr[4][2];
#pragma unroll
    for (int mt = 0; mt < 4; ++mt) {
      int r = wm * 64 + mt * 16 + lr;
#pragma unroll
      for (int kc = 0; kc < 2; ++kc) {
        int c = kc * 4 + q;
        af[mt][kc] = *(const bf16x8*)(smAb + (r << 7) + ((c ^ (r & 7)) << 4));
      }
    }
#pragma unroll
    for (int nt = 0; nt < 4; ++nt) {
      int r = wn * 64 + nt * 16 + lr;
#pragma unroll
      for (int kc = 0; kc < 2; ++kc) {
        int c = kc * 4 + q;
        bfr[nt][kc] = *(const bf16x8*)(smBb + (r << 7) + ((c ^ (r & 7)) << 4));
      }
    }

    // ---- MFMA: K=64, 32 MFMAs/wave ----
#pragma unroll
    for (int kc = 0; kc < 2; ++kc) {
#pragma unroll
      for (int mt = 0; mt < 4; ++mt) {
#pragma unroll
        for (int nt = 0; nt < 4; ++nt) {
          acc[mt][nt] = __builtin_amdgcn_mfma_f32_16x16x32_bf16(
              af[mt][kc], bfr[nt][kc], acc[mt][nt], 0, 0, 0);
        }
      }
    }

    // ---- epilogue ----
    float lane_sum = 0.0f;
    if (deg == 3) {
      if (diag) {
        // full tile, column weight a_j only (covers both triangles of I x I)
#pragma unroll
        for (int nt = 0; nt < 4; ++nt) {
          f32x2 cs = {0.0f, 0.0f};
#pragma unroll
          for (int mt = 0; mt < 4; ++mt) {
#pragma unroll
            for (int h = 0; h < 2; ++h) {
              f32x2 T = {acc[mt][nt][2 * h], acc[mt][nt][2 * h + 1]};
              f32x2 T2 = T * T;
              cs += T2 * T;  // pk_fma
            }
          }
          lane_sum = fmaf(cs.x + cs.y, wcol[nt], lane_sum);
        }
      } else {
        // off-diagonal: weight (a_i + a_j) via col-sums and row-sums
        f32x2 rsum[4][2];
#pragma unroll
        for (int mt = 0; mt < 4; ++mt)
          for (int h = 0; h < 2; ++h) rsum[mt][h] = (f32x2){0.0f, 0.0f};
#pragma unroll
        for (int nt = 0; nt < 4; ++nt) {
          f32x2 cs = {0.0f, 0.0f};
#pragma unroll
          for (int mt = 0; mt < 4; ++mt) {
#pragma unroll
            for (int h = 0; h < 2; ++h) {
              f32x2 T = {acc[mt][nt][2 * h], acc[mt][nt][2 * h + 1]};
              f32x2 T2 = T * T;
              f32x2 P = T2 * T;
              cs += P;
              rsum[mt][h] += P;
            }
          }
          lane_sum = fmaf(cs.x + cs.y, wcol[nt], lane_sum);
        }
#pragma unroll
        for (int mt = 0; mt < 4; ++mt) {
          f32x2 a0 = {arow[mt].x, arow[mt].y};
          f32x2 a1 = {arow[mt].z, arow[mt].w};
          f32x2 r2 = rsum[mt][0] * a0 + rsum[mt][1] * a1;
          lane_sum += r2.x + r2.y;
        }
      }
    } else {
      // generic degree (runtime fallback; even degree needs sign restore)
      const float* yr;
#pragma unroll
      for (int nt = 0; nt < 4; ++nt) {
        float cs = 0.0f;
#pragma unroll
        for (int mt = 0; mt < 4; ++mt) {
          yr = (const float*)&yrow[mt];
          const float* ar = (const float*)&arow[mt];
#pragma unroll
          for (int rg = 0; rg < 4; ++rg) {
            float T = acc[mt][nt][rg];
            float p = 1.0f;
            for (int d = 0; d < deg; ++d) p *= T;
            if (!(deg & 1)) p *= yr[rg] * ycol[nt];
            cs += p;
            if (!diag) lane_sum += p * ar[rg];  // row weight a_i
          }
        }
        lane_sum = fmaf(cs, wcol[nt], lane_sum);
      }
    }

    // ---- block reduce ----
#pragma unroll
    for (int off = 32; off > 0; off >>= 1)
      lane_sum += __shfl_down(lane_sum, off, 64);
    if (lane == 0) wred[wv] = lane_sum;
    __syncthreads();
    if (tid == 0) blocksum = wred[0] + wred[1] + wred[2] + wred[3];
  }

  // ---- ticket: every dispatched block increments; last one finalizes ----
  if (tid == 0) {
    if (active) atomicAdd(&accs->tsum, blocksum);
    __threadfence();
    unsigned old = atomicAdd(&accs->cnt, 1u);
    if (old == TOTAL_BLOCKS - 1) {
      __threadfence();
      double T = (double)atomicAdd(&accs->tsum, 0.0f);  // coherent read
      double A = (double)atomicAdd(&accs->sa, 0.0f);
      double X = (double)atomicAdd(&accs->sxi, 0.0f);
      double Y = (double)atomicAdd(&accs->sy, 0.0f);
      double b = (double)bp[0];
      double Cc = (double)Cp[0];
      double lam = (double)lamp[0];
      double mean = (T + b * Y - (double)N_SAMP + X) / (double)N_SAMP;
      out[0] = (float)(0.5 * A + Cc * X + lam * mean);
    }
  }
}

extern "C" void kernel_launch(void* const* d_in, const int* in_sizes, int n_in,
                              void* d_out, int out_size, void* d_ws,
                              size_t ws_size, hipStream_t stream) {
  const float* x = (const float*)d_in[0];
  const float* y = (const float*)d_in[1];
  const float* alpha = (const float*)d_in[2];
  const float* xi = (const float*)d_in[3];
  const float* b = (const float*)d_in[4];
  const int* coeff = (const int*)d_in[5];
  const int* degree = (const int*)d_in[6];
  const int* C = (const int*)d_in[7];
  const int* lambd = (const int*)d_in[8];

  unsigned short* xb = (unsigned short*)d_ws;  // 2 MB
  Accs* accs = (Accs*)((char*)d_ws + (size_t)N_SAMP * D_FEAT * 2);

  hipMemsetAsync(accs, 0, sizeof(Accs), stream);  // zero atomics (capture-safe)

  prep_kernel<<<(N_SAMP * D_FEAT) / (4 * 256), 256, 0, stream>>>(x, y, alpha,
                                                                 xi, xb, accs);

  dim3 grid(NTILE, NTILE);
  tile_kernel<<<grid, 256, 0, stream>>>(xb, alpha, y, coeff, degree, b, C,
                                        lambd, accs, (float*)d_out);
}

// Round 3
// 129.426 us; speedup vs baseline: 3.3156x; 3.3156x over previous
//
#include <hip/hip_runtime.h>
#include <math.h>

#define N_SAMP 16384
#define D_FEAT 64
#define TILE 128
#define NTILE (N_SAMP / TILE)                    // 128
#define NBLK (NTILE * (NTILE + 1) / 2)           // 8256 upper-triangle tiles

typedef __attribute__((ext_vector_type(8))) short bf16x8;
typedef __attribute__((ext_vector_type(4))) float f32x4;
typedef __attribute__((ext_vector_type(2))) float f32x2;
typedef __attribute__((ext_vector_type(4))) unsigned short u16x4;

typedef __attribute__((address_space(3))) unsigned lds_u32_t;
typedef const __attribute__((address_space(1))) unsigned glb_u32_t;

struct Accs {
  float sa, sxi, sy;
  unsigned pad;
};

__device__ __forceinline__ void load16_to_lds(const void* g, void* l) {
  __builtin_amdgcn_global_load_lds((glb_u32_t*)g, (lds_u32_t*)l, 16, 0, 0);
}

__device__ __forceinline__ unsigned short f2bf_rne(float f) {
  union { float f; unsigned u; } v;
  v.f = f;
  unsigned u = v.u;
  return (unsigned short)((u + 0x7FFFu + ((u >> 16) & 1u)) >> 16);
}

// Prepass: xb[i][k] = bf16(y_i * x[i][k]); fused Sa/Sxi/Sy reductions
// (64 blocks x 3 atomics — no contention).
__global__ __launch_bounds__(256) void prep_kernel(
    const float* __restrict__ x, const float* __restrict__ y,
    const float* __restrict__ alpha, const float* __restrict__ xi,
    unsigned short* __restrict__ xb, Accs* __restrict__ accs) {
  int t = blockIdx.x * 256 + threadIdx.x;  // 0 .. 262143
  int base = t * 4;
  int row = base >> 6;  // D=64
  float yv = y[row];
  float4 v = *(const float4*)(x + base);
  u16x4 o;
  o.x = f2bf_rne(v.x * yv);
  o.y = f2bf_rne(v.y * yv);
  o.z = f2bf_rne(v.z * yv);
  o.w = f2bf_rne(v.w * yv);
  *(u16x4*)(xb + base) = o;

  if (blockIdx.x < (N_SAMP / 256)) {
    float a = fmaxf(alpha[t], 0.0f);
    float xr = fmaxf(xi[t], 0.0f);
    float yy = y[t];
#pragma unroll
    for (int off = 32; off > 0; off >>= 1) {
      a += __shfl_down(a, off, 64);
      xr += __shfl_down(xr, off, 64);
      yy += __shfl_down(yy, off, 64);
    }
    if ((threadIdx.x & 63) == 0) {
      atomicAdd(&accs->sa, a);
      atomicAdd(&accs->sxi, xr);
      atomicAdd(&accs->sy, yy);
    }
  }
}

// Upper-triangle tiles only; off-diagonal tiles weighted by (a_i + a_j).
// acc init = y_i*y_j*coeff; MFMA adds (y_i x_i)·(y_j x_j) =>
// T = y_i y_j (g+coeff); odd degree => T^d = y_i y_j K^d.
// One plain store per block — NO global atomics (R2's 5.6x regression).
__global__ __launch_bounds__(256, 2) void tile_kernel(
    const unsigned short* __restrict__ xb,
    const float* __restrict__ alpha,
    const float* __restrict__ y,
    const int* __restrict__ coeffp,
    const int* __restrict__ degp,
    float* __restrict__ partials) {
  __shared__ unsigned short smA[128 * 64];
  __shared__ unsigned short smB[128 * 64];
  __shared__ float wred[4];

  const int tid = threadIdx.x;

  // ---- triangular decode: block t -> (ti <= tj) ----
  const int t = blockIdx.x;
  const double M = 2.0 * NTILE + 1.0;  // 257
  int ti = (int)((M - sqrt(M * M - 8.0 * (double)t)) * 0.5);
  while (ti > 0 && (ti * NTILE - ti * (ti - 1) / 2) > t) --ti;
  while (((ti + 1) * NTILE - (ti + 1) * ti / 2) <= t) ++ti;
  const int tj = ti + (t - (ti * NTILE - ti * (ti - 1) / 2));
  const int I0 = ti * 128;
  const int J0 = tj * 128;
  const bool diag = (ti == tj);

  const int lane = tid & 63;
  const int wv = tid >> 6;  // wave 0..3
  const int wm = wv >> 1;   // wave row (0..1)
  const int wn = wv & 1;    // wave col (0..1)
  const int lr = lane & 15;
  const int q = lane >> 4;  // quad 0..3

  // ---- stage A (rows I0..) and B (rows J0..) tiles, XOR-swizzled ----
  const char* xbytes = (const char*)xb;
  char* smAb = (char*)smA;
  char* smBb = (char*)smB;
#pragma unroll
  for (int it = 0; it < 4; ++it) {
    int slotbase = it * 256 + wv * 64;  // wave-uniform
    int S = slotbase + lane;
    int r = S >> 3;
    int c = (S & 7) ^ (r & 7);
    load16_to_lds(xbytes + (((size_t)(I0 + r)) << 7) + (c << 4),
                  smAb + (slotbase << 4));
    load16_to_lds(xbytes + (((size_t)(J0 + r)) << 7) + (c << 4),
                  smBb + (slotbase << 4));
  }

  const float fco = (float)coeffp[0];
  const int deg = degp[0];

  float4 yrow[4];
  float4 arow[4];
  float ycol[4], wcol[4];
#pragma unroll
  for (int mt = 0; mt < 4; ++mt) {
    int i = I0 + wm * 64 + mt * 16 + q * 4;
    yrow[mt] = *(const float4*)(y + i);
    float4 av = *(const float4*)(alpha + i);
    arow[mt].x = fmaxf(av.x, 0.0f);
    arow[mt].y = fmaxf(av.y, 0.0f);
    arow[mt].z = fmaxf(av.z, 0.0f);
    arow[mt].w = fmaxf(av.w, 0.0f);
  }
#pragma unroll
  for (int nt = 0; nt < 4; ++nt) {
    int j = J0 + wn * 64 + nt * 16 + lr;
    ycol[nt] = y[j];
    wcol[nt] = fmaxf(alpha[j], 0.0f);
  }

  // acc[mt][nt] element rg -> C[row = q*4+rg][col = lr] (m89/m91 layout)
  f32x4 acc[4][4];
#pragma unroll
  for (int mt = 0; mt < 4; ++mt) {
    f32x2 yr0 = {yrow[mt].x, yrow[mt].y};
    f32x2 yr1 = {yrow[mt].z, yrow[mt].w};
#pragma unroll
    for (int nt = 0; nt < 4; ++nt) {
      float s = ycol[nt] * fco;
      f32x2 lo = yr0 * s;
      f32x2 hi = yr1 * s;
      acc[mt][nt][0] = lo.x;
      acc[mt][nt][1] = lo.y;
      acc[mt][nt][2] = hi.x;
      acc[mt][nt][3] = hi.y;
    }
  }

  __syncthreads();  // drains global_load_lds (vmcnt)

  // ---- LDS -> frags: A[m=lr][k=q*8+j] ----
  bf16x8 af[4][2], bfr[4][2];
#pragma unroll
  for (int mt = 0; mt < 4; ++mt) {
    int r = wm * 64 + mt * 16 + lr;
#pragma unroll
    for (int kc = 0; kc < 2; ++kc) {
      int c = kc * 4 + q;
      af[mt][kc] = *(const bf16x8*)(smAb + (r << 7) + ((c ^ (r & 7)) << 4));
    }
  }
#pragma unroll
  for (int nt = 0; nt < 4; ++nt) {
    int r = wn * 64 + nt * 16 + lr;
#pragma unroll
    for (int kc = 0; kc < 2; ++kc) {
      int c = kc * 4 + q;
      bfr[nt][kc] = *(const bf16x8*)(smBb + (r << 7) + ((c ^ (r & 7)) << 4));
    }
  }

  // ---- MFMA: K=64, 32 MFMAs/wave ----
#pragma unroll
  for (int kc = 0; kc < 2; ++kc) {
#pragma unroll
    for (int mt = 0; mt < 4; ++mt) {
#pragma unroll
      for (int nt = 0; nt < 4; ++nt) {
        acc[mt][nt] = __builtin_amdgcn_mfma_f32_16x16x32_bf16(
            af[mt][kc], bfr[nt][kc], acc[mt][nt], 0, 0, 0);
      }
    }
  }

  // ---- epilogue ----
  float lane_sum = 0.0f;
  if (deg == 3) {
    if (diag) {
      // full tile, column weight a_j only: 2 packed insts / 2 elems
#pragma unroll
      for (int nt = 0; nt < 4; ++nt) {
        f32x2 cs = {0.0f, 0.0f};
#pragma unroll
        for (int mt = 0; mt < 4; ++mt) {
#pragma unroll
          for (int h = 0; h < 2; ++h) {
            f32x2 T = {acc[mt][nt][2 * h], acc[mt][nt][2 * h + 1]};
            f32x2 T2 = T * T;
            cs += T2 * T;  // pk_fma
          }
        }
        lane_sum = fmaf(cs.x + cs.y, wcol[nt], lane_sum);
      }
    } else {
      // off-diagonal, weight (a_i + a_j): 3 packed insts / 2 elems
      f32x2 rsum[4][2];
#pragma unroll
      for (int mt = 0; mt < 4; ++mt)
        for (int h = 0; h < 2; ++h) rsum[mt][h] = (f32x2){0.0f, 0.0f};
#pragma unroll
      for (int nt = 0; nt < 4; ++nt) {
        f32x2 cs = {0.0f, 0.0f};
#pragma unroll
        for (int mt = 0; mt < 4; ++mt) {
#pragma unroll
          for (int h = 0; h < 2; ++h) {
            f32x2 T = {acc[mt][nt][2 * h], acc[mt][nt][2 * h + 1]};
            f32x2 T2 = T * T;
            cs += T2 * T;            // pk_fma
            rsum[mt][h] += T2 * T;   // pk_fma (T2 reused)
          }
        }
        lane_sum = fmaf(cs.x + cs.y, wcol[nt], lane_sum);
      }
#pragma unroll
      for (int mt = 0; mt < 4; ++mt) {
        f32x2 a0 = {arow[mt].x, arow[mt].y};
        f32x2 a1 = {arow[mt].z, arow[mt].w};
        f32x2 r2 = rsum[mt][0] * a0 + rsum[mt][1] * a1;
        lane_sum += r2.x + r2.y;
      }
    }
  } else {
    // generic degree fallback (even degree restores the y_i y_j sign)
#pragma unroll
    for (int nt = 0; nt < 4; ++nt) {
      float cs = 0.0f;
#pragma unroll
      for (int mt = 0; mt < 4; ++mt) {
        const float* yr = (const float*)&yrow[mt];
        const float* ar = (const float*)&arow[mt];
#pragma unroll
        for (int rg = 0; rg < 4; ++rg) {
          float T = acc[mt][nt][rg];
          float p = 1.0f;
          for (int d = 0; d < deg; ++d) p *= T;
          if (!(deg & 1)) p *= yr[rg] * ycol[nt];
          cs += p;
          if (!diag) lane_sum += p * ar[rg];  // row weight a_i
        }
      }
      lane_sum = fmaf(cs, wcol[nt], lane_sum);
    }
  }

  // ---- block reduce -> one plain store per tile ----
#pragma unroll
  for (int off = 32; off > 0; off >>= 1)
    lane_sum += __shfl_down(lane_sum, off, 64);
  if (lane == 0) wred[wv] = lane_sum;
  __syncthreads();
  if (tid == 0)
    partials[t] = wred[0] + wred[1] + wred[2] + wred[3];
}

__global__ __launch_bounds__(1024) void finalize_kernel(
    const float* __restrict__ partials,
    const Accs* __restrict__ accs,
    const float* __restrict__ bp,
    const int* __restrict__ Cp,
    const int* __restrict__ lamp,
    float* __restrict__ out) {
  double tsum = 0.0;
  for (int i = threadIdx.x; i < NBLK; i += 1024) tsum += (double)partials[i];
#pragma unroll
  for (int off = 32; off > 0; off >>= 1)
    tsum += __shfl_down(tsum, off, 64);
  __shared__ double red[16];
  int wv = threadIdx.x >> 6;
  if ((threadIdx.x & 63) == 0) red[wv] = tsum;
  __syncthreads();
  if (threadIdx.x == 0) {
    double T = 0;
    for (int k = 0; k < 16; ++k) T += red[k];
    double A = (double)accs->sa;
    double X = (double)accs->sxi;
    double Y = (double)accs->sy;
    double b = (double)bp[0];
    double Cc = (double)Cp[0];
    double lam = (double)lamp[0];
    double mean = (T + b * Y - (double)N_SAMP + X) / (double)N_SAMP;
    out[0] = (float)(0.5 * A + Cc * X + lam * mean);
  }
}

extern "C" void kernel_launch(void* const* d_in, const int* in_sizes, int n_in,
                              void* d_out, int out_size, void* d_ws,
                              size_t ws_size, hipStream_t stream) {
  const float* x = (const float*)d_in[0];
  const float* y = (const float*)d_in[1];
  const float* alpha = (const float*)d_in[2];
  const float* xi = (const float*)d_in[3];
  const float* b = (const float*)d_in[4];
  const int* coeff = (const int*)d_in[5];
  const int* degree = (const int*)d_in[6];
  const int* C = (const int*)d_in[7];
  const int* lambd = (const int*)d_in[8];

  unsigned short* xb = (unsigned short*)d_ws;  // 2 MB
  char* p = (char*)d_ws + (size_t)N_SAMP * D_FEAT * 2;
  float* partials = (float*)p;                 // 8256 floats
  Accs* accs = (Accs*)(p + ((NBLK * 4 + 255) & ~255));

  hipMemsetAsync(accs, 0, sizeof(Accs), stream);

  prep_kernel<<<(N_SAMP * D_FEAT) / (4 * 256), 256, 0, stream>>>(x, y, alpha,
                                                                 xi, xb, accs);

  tile_kernel<<<NBLK, 256, 0, stream>>>(xb, alpha, y, coeff, degree, partials);

  finalize_kernel<<<1, 1024, 0, stream>>>(partials, accs, b, C, lambd,
                                          (float*)d_out);
}

// Round 5
// 117.216 us; speedup vs baseline: 3.6610x; 1.1042x over previous
//
#include <hip/hip_runtime.h>

#define N_SAMP 16384
#define D_FEAT 64
#define TILE 128
#define NTILE 128                   // 128 tile-rows
#define SPLIT 8                     // blocks per row-pair
#define NPAIR (NTILE / 2)           // 64
#define NBLOCKS (NPAIR * SPLIT)     // 512 blocks, exactly 2/CU
#define TPP (NTILE + 1)             // 129 tiles per pair (constant!)
#define SEG_BASE (TPP / SPLIT)      // 16
#define SEG_REM (TPP % SPLIT)       // 1
#define BUFBYTES (TILE * D_FEAT * 2)  // 16 KiB per B buffer

typedef __attribute__((ext_vector_type(8))) short bf16x8;
typedef __attribute__((ext_vector_type(4))) float f32x4;
typedef __attribute__((ext_vector_type(2))) float f32x2;
typedef __attribute__((ext_vector_type(4))) unsigned short u16x4;

typedef __attribute__((address_space(3))) unsigned lds_u32_t;
typedef const __attribute__((address_space(1))) unsigned glb_u32_t;

struct Accs {
  float sa, sxi, sy;
  unsigned pad;
};

__device__ __forceinline__ void load16_to_lds(const void* g, void* l) {
  __builtin_amdgcn_global_load_lds((glb_u32_t*)g, (lds_u32_t*)l, 16, 0, 0);
}

__device__ __forceinline__ unsigned short f2bf_rne(float f) {
  union { float f; unsigned u; } v;
  v.f = f;
  unsigned u = v.u;
  return (unsigned short)((u + 0x7FFFu + ((u >> 16) & 1u)) >> 16);
}

// Prepass: xb[i][k] = bf16(y_i * x[i][k]); fused Sa/Sxi/Sy (64 blocks x 3
// atomics — uncontended; R2 showed same-line atomics serialize ~10ns each).
__global__ __launch_bounds__(256) void prep_kernel(
    const float* __restrict__ x, const float* __restrict__ y,
    const float* __restrict__ alpha, const float* __restrict__ xi,
    unsigned short* __restrict__ xb, Accs* __restrict__ accs) {
  int t = blockIdx.x * 256 + threadIdx.x;  // 0 .. 262143
  int base = t * 4;
  int row = base >> 6;  // D=64
  float yv = y[row];
  float4 v = *(const float4*)(x + base);
  u16x4 o;
  o.x = f2bf_rne(v.x * yv);
  o.y = f2bf_rne(v.y * yv);
  o.z = f2bf_rne(v.z * yv);
  o.w = f2bf_rne(v.w * yv);
  *(u16x4*)(xb + base) = o;

  if (blockIdx.x < (N_SAMP / 256)) {
    float a = fmaxf(alpha[t], 0.0f);
    float xr = fmaxf(xi[t], 0.0f);
    float yy = y[t];
#pragma unroll
    for (int off = 32; off > 0; off >>= 1) {
      a += __shfl_down(a, off, 64);
      xr += __shfl_down(xr, off, 64);
      yy += __shfl_down(yy, off, 64);
    }
    if ((threadIdx.x & 63) == 0) {
      atomicAdd(&accs->sa, a);
      atomicAdd(&accs->sxi, xr);
      atomicAdd(&accs->sy, yy);
    }
  }
}

// Multi-tile K-loop: block = segment of a row-pair's 129 upper-triangle tiles.
// A frags in registers across the loop; B double-buffered (prefetch at iter
// start -> barrier at iter end finds vmcnt drained). Off-diag tiles weighted
// (a_i + a_j); rsum accumulates across tiles, flushed per row segment.
// T = y_i y_j (g+coeff) via acc-init; odd degree => T^d = y_i y_j K^d.
__global__ __launch_bounds__(256, 2) void tile_kernel(
    const unsigned short* __restrict__ xb,
    const float* __restrict__ alpha,
    const float* __restrict__ y,
    const int* __restrict__ coeffp,
    const int* __restrict__ degp,
    float* __restrict__ partials) {
  __shared__ unsigned short smA[TILE * D_FEAT];     // 16 KB
  __shared__ unsigned short smB[2][TILE * D_FEAT];  // 32 KB
  __shared__ float wred[4];

  const int tid = threadIdx.x;
  const int lane = tid & 63;
  const int wv = tid >> 6;  // wave 0..3
  const int wm = wv >> 1;   // wave row (0..1)
  const int wn = wv & 1;    // wave col (0..1)
  const int lr = lane & 15;
  const int q = lane >> 4;  // quad 0..3

  // ---- balanced schedule: pair p = {rows p, 127-p}, segment sb of SPLIT ----
  const int p = blockIdx.x >> 3;
  const int sb = blockIdx.x & (SPLIT - 1);
  const int i1 = p, i2 = NTILE - 1 - p;
  const int cnt1 = NTILE - p;  // tiles in row i1 (j = p..127)
  const int g0 = sb * SEG_BASE + (sb < SEG_REM ? sb : SEG_REM);
  const int gcnt = SEG_BASE + (sb < SEG_REM ? 1 : 0);

  const char* xbytes = (const char*)xb;
  char* smAb = (char*)smA;
  char* smBbase = (char*)smB;  // buffer k at smBbase + k*BUFBYTES

  const float fco = (float)coeffp[0];
  const int deg = degp[0];

  // per-thread staging offsets: 16B chunk (r,c) -> LDS slot r*8 + (c^(r&7))
  int goff[4];
#pragma unroll
  for (int it2 = 0; it2 < 4; ++it2) {
    int S = it2 * 256 + wv * 64 + lane;
    int r = S >> 3;
    int c = (S & 7) ^ (r & 7);
    goff[it2] = (r << 7) + (c << 4);
  }
  auto stage = [&](int rowtile, char* dst) {
    size_t tbase = ((size_t)rowtile) << 14;  // rowtile * 128 rows * 128 B
#pragma unroll
    for (int it2 = 0; it2 < 4; ++it2)
      load16_to_lds(xbytes + tbase + goff[it2],
                    dst + ((it2 * 256 + wv * 64) << 4));
  };

  f32x2 yr[4][2], ar[4][2];
  auto load_rows = [&](int ic) {
#pragma unroll
    for (int mt = 0; mt < 4; ++mt) {
      int idx = ic * TILE + wm * 64 + mt * 16 + q * 4;
      float4 yv = *(const float4*)(y + idx);
      float4 av = *(const float4*)(alpha + idx);
      yr[mt][0] = (f32x2){yv.x, yv.y};
      yr[mt][1] = (f32x2){yv.z, yv.w};
      ar[mt][0] = (f32x2){fmaxf(av.x, 0.0f), fmaxf(av.y, 0.0f)};
      ar[mt][1] = (f32x2){fmaxf(av.z, 0.0f), fmaxf(av.w, 0.0f)};
    }
  };

  bf16x8 af[4][2];
  auto read_af = [&]() {
#pragma unroll
    for (int mt = 0; mt < 4; ++mt) {
      int r = wm * 64 + mt * 16 + lr;
#pragma unroll
      for (int kc = 0; kc < 2; ++kc) {
        int c = kc * 4 + q;
        af[mt][kc] = *(const bf16x8*)(smAb + (r << 7) + ((c ^ (r & 7)) << 4));
      }
    }
  };

  f32x2 rsum[4][2];
#pragma unroll
  for (int mt = 0; mt < 4; ++mt)
    for (int h = 0; h < 2; ++h) rsum[mt][h] = (f32x2){0.0f, 0.0f};
  float lane_total = 0.0f;

  auto flush_rsum = [&]() {
#pragma unroll
    for (int mt = 0; mt < 4; ++mt) {
      f32x2 s = rsum[mt][0] * ar[mt][0] + rsum[mt][1] * ar[mt][1];
      lane_total += s.x + s.y;
      rsum[mt][0] = (f32x2){0.0f, 0.0f};
      rsum[mt][1] = (f32x2){0.0f, 0.0f};
    }
  };

  // ---- prologue: stage A(i of first tile) + B(first j) ----
  int ifirst = (g0 < cnt1) ? i1 : i2;
  int jfirst = (g0 < cnt1) ? (p + g0) : (i2 + (g0 - cnt1));
  stage(ifirst, smAb);
  stage(jfirst, smBbase);
  load_rows(ifirst);
  __syncthreads();
  read_af();
  // hazard guard: if iter 0 will restage A, af reads must be fenced first
  bool nswitch0 = (gcnt > 1) && ((g0 < cnt1) != (g0 + 1 < cnt1));
  if (nswitch0) __syncthreads();

  bool pend_switch = false;

  for (int it = 0; it < gcnt; ++it) {
    int g = g0 + it;
    int i = (g < cnt1) ? i1 : i2;
    int j = (g < cnt1) ? (p + g) : (i2 + (g - cnt1));
    char* bufc = smBbase + ((it & 1) * BUFBYTES);
    char* bufn = smBbase + (((it & 1) ^ 1) * BUFBYTES);

    if (pend_switch) {
      flush_rsum();      // old i's row weights
      load_rows(i);      // new row data
      read_af();         // A restaged last iter, drained by last barrier
      pend_switch = false;
    }

    // ---- prefetch next tile (in flight across this iter's compute) ----
    bool nswitch = false;
    if (it + 1 < gcnt) {
      int gn = g + 1;
      int inext = (gn < cnt1) ? i1 : i2;
      int jn = (gn < cnt1) ? (p + gn) : (i2 + (gn - cnt1));
      stage(jn, bufn);
      if (inext != i) {
        stage(inext, smAb);
        nswitch = true;
      }
    }

    // ---- column data ----
    float ycol[4], wcol[4];
#pragma unroll
    for (int nt = 0; nt < 4; ++nt) {
      int jj = j * TILE + wn * 64 + nt * 16 + lr;
      ycol[nt] = y[jj];
      wcol[nt] = fmaxf(alpha[jj], 0.0f);
    }

    // ---- acc init: y_i * y_j * coeff ----
    f32x4 acc[4][4];
#pragma unroll
    for (int mt = 0; mt < 4; ++mt) {
#pragma unroll
      for (int nt = 0; nt < 4; ++nt) {
        float s = ycol[nt] * fco;
        f32x2 lo = yr[mt][0] * s;
        f32x2 hi = yr[mt][1] * s;
        acc[mt][nt][0] = lo.x;
        acc[mt][nt][1] = lo.y;
        acc[mt][nt][2] = hi.x;
        acc[mt][nt][3] = hi.y;
      }
    }

    // ---- B frags from current buffer ----
    bf16x8 bfr[4][2];
#pragma unroll
    for (int nt = 0; nt < 4; ++nt) {
      int r = wn * 64 + nt * 16 + lr;
#pragma unroll
      for (int kc = 0; kc < 2; ++kc) {
        int c = kc * 4 + q;
        bfr[nt][kc] = *(const bf16x8*)(bufc + (r << 7) + ((c ^ (r & 7)) << 4));
      }
    }

    // ---- MFMA: K=64, 32 MFMAs/wave ----
#pragma unroll
    for (int kc = 0; kc < 2; ++kc) {
#pragma unroll
      for (int mt = 0; mt < 4; ++mt) {
#pragma unroll
        for (int nt = 0; nt < 4; ++nt) {
          acc[mt][nt] = __builtin_amdgcn_mfma_f32_16x16x32_bf16(
              af[mt][kc], bfr[nt][kc], acc[mt][nt], 0, 0, 0);
        }
      }
    }

    // ---- epilogue ----
    bool diagonal = (j == i);
    if (deg == 3) {
      if (diagonal) {
#pragma unroll
        for (int nt = 0; nt < 4; ++nt) {
          f32x2 cs = {0.0f, 0.0f};
#pragma unroll
          for (int mt = 0; mt < 4; ++mt) {
#pragma unroll
            for (int h = 0; h < 2; ++h) {
              f32x2 T = {acc[mt][nt][2 * h], acc[mt][nt][2 * h + 1]};
              f32x2 T2 = T * T;
              cs += T2 * T;
            }
          }
          lane_total = fmaf(cs.x + cs.y, wcol[nt], lane_total);
        }
      } else {
#pragma unroll
        for (int nt = 0; nt < 4; ++nt) {
          f32x2 cs = {0.0f, 0.0f};
#pragma unroll
          for (int mt = 0; mt < 4; ++mt) {
#pragma unroll
            for (int h = 0; h < 2; ++h) {
              f32x2 T = {acc[mt][nt][2 * h], acc[mt][nt][2 * h + 1]};
              f32x2 T2 = T * T;
              f32x2 P = T2 * T;
              cs += P;
              rsum[mt][h] += P;  // row-weighted at flush (a_i fixed per row)
            }
          }
          lane_total = fmaf(cs.x + cs.y, wcol[nt], lane_total);
        }
      }
    } else {
      // generic-degree fallback (even degree restores y_i y_j sign)
#pragma unroll
      for (int nt = 0; nt < 4; ++nt) {
        float cs = 0.0f;
#pragma unroll
        for (int mt = 0; mt < 4; ++mt) {
          float ys[4] = {yr[mt][0].x, yr[mt][0].y, yr[mt][1].x, yr[mt][1].y};
          float as[4] = {ar[mt][0].x, ar[mt][0].y, ar[mt][1].x, ar[mt][1].y};
#pragma unroll
          for (int rg = 0; rg < 4; ++rg) {
            float T = acc[mt][nt][rg];
            float pw = 1.0f;
            for (int d = 0; d < deg; ++d) pw *= T;
            if (!(deg & 1)) pw *= ys[rg] * ycol[nt];
            cs += pw;
            if (!diagonal) lane_total += pw * as[rg];
          }
        }
        lane_total = fmaf(cs, wcol[nt], lane_total);
      }
    }

    __syncthreads();  // drains prefetch (long since landed) + orders LDS reuse
    pend_switch = nswitch;
  }

  flush_rsum();  // current segment's row weights

  // ---- one block reduce + one store per block ----
#pragma unroll
  for (int off = 32; off > 0; off >>= 1)
    lane_total += __shfl_down(lane_total, off, 64);
  if (lane == 0) wred[wv] = lane_total;
  __syncthreads();
  if (tid == 0)
    partials[blockIdx.x] = wred[0] + wred[1] + wred[2] + wred[3];
}

__global__ __launch_bounds__(256) void finalize_kernel(
    const float* __restrict__ partials,
    const Accs* __restrict__ accs,
    const float* __restrict__ bp,
    const int* __restrict__ Cp,
    const int* __restrict__ lamp,
    float* __restrict__ out) {
  double tsum = 0.0;
  for (int i = threadIdx.x; i < NBLOCKS; i += 256) tsum += (double)partials[i];
#pragma unroll
  for (int off = 32; off > 0; off >>= 1)
    tsum += __shfl_down(tsum, off, 64);
  __shared__ double red[4];
  int wv = threadIdx.x >> 6;
  if ((threadIdx.x & 63) == 0) red[wv] = tsum;
  __syncthreads();
  if (threadIdx.x == 0) {
    double T = red[0] + red[1] + red[2] + red[3];
    double A = (double)accs->sa;
    double X = (double)accs->sxi;
    double Y = (double)accs->sy;
    double b = (double)bp[0];
    double Cc = (double)Cp[0];
    double lam = (double)lamp[0];
    double mean = (T + b * Y - (double)N_SAMP + X) / (double)N_SAMP;
    out[0] = (float)(0.5 * A + Cc * X + lam * mean);
  }
}

extern "C" void kernel_launch(void* const* d_in, const int* in_sizes, int n_in,
                              void* d_out, int out_size, void* d_ws,
                              size_t ws_size, hipStream_t stream) {
  const float* x = (const float*)d_in[0];
  const float* y = (const float*)d_in[1];
  const float* alpha = (const float*)d_in[2];
  const float* xi = (const float*)d_in[3];
  const float* b = (const float*)d_in[4];
  const int* coeff = (const int*)d_in[5];
  const int* degree = (const int*)d_in[6];
  const int* C = (const int*)d_in[7];
  const int* lambd = (const int*)d_in[8];

  unsigned short* xb = (unsigned short*)d_ws;  // 2 MB
  char* pbase = (char*)d_ws + (size_t)N_SAMP * D_FEAT * 2;
  float* partials = (float*)pbase;  // 512 floats
  Accs* accs = (Accs*)(pbase + ((NBLOCKS * 4 + 255) & ~255));

  (void)hipMemsetAsync(accs, 0, sizeof(Accs), stream);

  prep_kernel<<<(N_SAMP * D_FEAT) / (4 * 256), 256, 0, stream>>>(x, y, alpha,
                                                                 xi, xb, accs);

  tile_kernel<<<NBLOCKS, 256, 0, stream>>>(xb, alpha, y, coeff, degree,
                                           partials);

  finalize_kernel<<<1, 256, 0, stream>>>(partials, accs, b, C, lambd,
                                         (float*)d_out);
}